// Round 9
// baseline (99.496 us; speedup 1.0000x reference)
//
#include <hip/hip_runtime.h>
#include <hip/hip_bf16.h>
#include <stdint.h>

#define M_DIM 8192
#define N_DIM 2048
#define K_DIM 2048

typedef __attribute__((ext_vector_type(8))) short bf16x8;
typedef __attribute__((ext_vector_type(8))) short short8;
typedef __attribute__((ext_vector_type(4))) float f32x4;
typedef __attribute__((ext_vector_type(16))) float f32x16;

static __device__ __forceinline__ unsigned short f2bf(float f) {
  union { float f; unsigned u; } a; a.f = f;
  unsigned u = a.u;
  u += 0x7FFFu + ((u >> 16) & 1u);   // round-to-nearest-even
  return (unsigned short)(u >> 16);
}

static __device__ __forceinline__ void async16(void* lds, const void* g) {
  __builtin_amdgcn_global_load_lds(
      (const __attribute__((address_space(1))) unsigned int*)g,
      (__attribute__((address_space(3))) unsigned int*)lds, 16, 0, 0);
}

#define BAR()                                \
  do {                                       \
    asm volatile("" ::: "memory");           \
    __builtin_amdgcn_s_barrier();            \
    asm volatile("" ::: "memory");           \
  } while (0)
#define VMCNT(n) asm volatile("s_waitcnt vmcnt(" #n ")" ::: "memory")

// ---- kernel 1: convert + transpose W [K][N] -> Wt [N][K] bf16; fused
// W[:,0] extraction ----
__global__ __launch_bounds__(256) void k_transW(const float* __restrict__ W,
                                                unsigned short* __restrict__ Wt,
                                                float* __restrict__ wcol) {
  __shared__ float tile[64][65];
  const int bx = blockIdx.x & 31;
  const int by = blockIdx.x >> 5;
  const int n0 = bx * 64, k0 = by * 64;
  const int t = threadIdx.x;
  #pragma unroll
  for (int i = 0; i < 16; ++i) {
    int lin = i * 256 + t;
    int r = lin >> 6, c = lin & 63;
    float v = W[(size_t)(k0 + r) * N_DIM + n0 + c];
    tile[r][c] = v;
    if (bx == 0 && c == 0) wcol[k0 + r] = v;
  }
  __syncthreads();
  #pragma unroll
  for (int i = 0; i < 16; ++i) {
    int lin = i * 256 + t;
    int r = lin >> 6, c = lin & 63;
    Wt[(size_t)(n0 + r) * K_DIM + k0 + c] = f2bf(tile[c][r]);
  }
}

// ---- kernel 2: X fp32->bf16 + fused fp64 row-dot with W[:,0] -> adj ----
__global__ __launch_bounds__(256) void k_convX(const float* __restrict__ X,
    const float* __restrict__ wcol, const float* __restrict__ b,
    unsigned short* __restrict__ Xb, float* __restrict__ adj) {
  const int m = blockIdx.x;
  const int t = threadIdx.x;
  const float4* xr = (const float4*)(X + (size_t)m * K_DIM);
  const float4* wc = (const float4*)wcol;
  float4 x0 = xr[2 * t], x1 = xr[2 * t + 1];
  float4 w0 = wc[2 * t], w1 = wc[2 * t + 1];
  short8 o;
  o[0] = (short)f2bf(x0.x); o[1] = (short)f2bf(x0.y);
  o[2] = (short)f2bf(x0.z); o[3] = (short)f2bf(x0.w);
  o[4] = (short)f2bf(x1.x); o[5] = (short)f2bf(x1.y);
  o[6] = (short)f2bf(x1.z); o[7] = (short)f2bf(x1.w);
  *(short8*)(Xb + (size_t)m * K_DIM + t * 8) = o;
  double s = (double)x0.x * w0.x + (double)x0.y * w0.y +
             (double)x0.z * w0.z + (double)x0.w * w0.w +
             (double)x1.x * w1.x + (double)x1.y * w1.y +
             (double)x1.z * w1.z + (double)x1.w * w1.w;
  #pragma unroll
  for (int off = 32; off > 0; off >>= 1) s += __shfl_down(s, off, 64);
  __shared__ double red[4];
  if ((t & 63) == 0) red[t >> 6] = s;
  __syncthreads();
  if (t == 0) {
    double tot = red[0] + red[1] + red[2] + red[3] + (double)b[0];
    adj[m] = (tot > 0.5) ? 1.0f : -1.0f;
  }
}

// ---- kernel 3: 256x256 MFMA GEMM, 32x32x16, READ-AHEAD 3-phase pipeline ----
// Data placement & sigma-mapping identical to rounds 7/8 (conflict-free,
// correct). NEW: fragments for cluster c are read ONE PHASE EARLY so ds_reads
// overlap MFMA; 3 barriers per K-tile.
// Clusters: C1=(MH0,NH0) C2=(0,1) C3=(1,0) C4=(1,1).
//  PhA: rd bv1(j);          stg B0(j+1);            C1;      vmcnt(4) BAR
//  PhB: rd af1(j);          stg B1(j+1),A1(j+1);    C2,C3;   vmcnt(4) BAR
//  PhC: rd af0,bv0(j+1);    stg A0(j+2);            C4;      vmcnt(4) BAR
// Queue trace (units of 2 loads, steady state): retire exactly the unit
// needed by the NEXT phase's read, one barrier ahead; all stage->retire
// distances >= 2 phases; all overwrite distances >= 2 barriers after last
// reader. Prologue stages {A0,B0,B1,A1}(0)+A0(1), vmcnt(4). Tail: j=30 with
// vmcnt(2)@PhC, j=31 drains vmcnt(0)@PhA.
__device__ __forceinline__ void stage_unit(char* ldsc,
    const unsigned short* __restrict__ src, int row0, int kt,
    int isB, int sel, int wid, int l) {
  char* base = ldsc + (size_t)(kt & 1) * 65536 + (size_t)isB * 32768;
  const int p = ((l >> 2) & 15) + 16 * (l & 1) + 32 * (((l >> 1) ^ (l >> 5)) & 1);
  #pragma unroll
  for (int j = 0; j < 2; ++j) {
    int idx = wid * 2 + j;             // [0,16) subtile slots of this unit
    int q = idx >> 2, sc = idx & 3;
    int sr = isB ? (q * 2 + sel) : ((q & 1) + sel * 2 + (q >> 1) * 4);
    int grow = row0 + sr * 32 + (p & 31);
    int gcol = kt * 64 + sc * 16 + (p >> 5) * 8;
    async16(base + (size_t)(sr * 4 + sc) * 1024,
            src + (size_t)grow * K_DIM + gcol);
  }
}

__global__ __launch_bounds__(512, 1) void k_gemm8(
    const unsigned short* __restrict__ A,   // Xb [M][K] bf16
    const unsigned short* __restrict__ B,   // Wt [N][K] bf16
    const float* __restrict__ bias,
    const float* __restrict__ adj,
    float* __restrict__ out) {
  __shared__ unsigned short lds[2 * 2 * 256 * 64];   // 128 KB
  char* ldsc = (char*)lds;

  const int t = threadIdx.x;
  const int wid = t >> 6, l = t & 63;
  const int wm = wid >> 2, wn = wid & 3;

  // XCD-bijective swizzle (nwg = 256, 256 % 8 == 0)
  const int bid = blockIdx.x;
  const int swz = (bid & 7) * 32 + (bid >> 3);
  const int bm = swz >> 3, bn = swz & 7;
  const int m0 = bm * 256, n0 = bn * 256;

  // verified-conflict-free per-lane read offset (slot sigma(l)*16)
  const int rloc = l & 15, qloc = l >> 4;
  const int rdoff = (rloc * 64 + qloc * 16) ^ ((rloc & 8) << 2);

  f32x16 acc[4][2] = {};

#define STG(isB, sel, kt) \
  stage_unit(ldsc, (isB) ? B : A, (isB) ? n0 : m0, kt, isB, sel, wid, l)

#define RD_A(DST, MH, ABUF)                                                 \
  _Pragma("unroll") for (int mb2 = 0; mb2 < 2; ++mb2) {                     \
    const char* abase = (ABUF) +                                            \
        (size_t)((wm * 4 + (MH) * 2 + mb2) * 4) * 1024 + rdoff;             \
    _Pragma("unroll") for (int ks = 0; ks < 4; ++ks)                        \
      DST[mb2][ks] = *(const bf16x8*)(abase + ks * 1024);                   \
  }

#define RD_B(DST, NH, BBUF)                                                 \
  {                                                                         \
    const char* bbase = (BBUF) +                                            \
        (size_t)((wn * 2 + (NH)) * 4) * 1024 + rdoff;                       \
    _Pragma("unroll") for (int ks = 0; ks < 4; ++ks)                        \
      DST[ks] = *(const bf16x8*)(bbase + ks * 1024);                        \
  }

#define MFMA_CL(MH, NH, AF, BV)                                             \
  __builtin_amdgcn_s_setprio(1);                                            \
  _Pragma("unroll") for (int ks = 0; ks < 4; ++ks)                          \
    _Pragma("unroll") for (int mb2 = 0; mb2 < 2; ++mb2)                     \
      acc[(MH) * 2 + mb2][NH] = __builtin_amdgcn_mfma_f32_32x32x16_bf16(    \
          AF[mb2][ks], BV[ks], acc[(MH) * 2 + mb2][NH], 0, 0, 0);           \
  __builtin_amdgcn_s_setprio(0);

  bf16x8 af0[2][4], af1[2][4], bv0[4], bv1[4];

  // ---- prologue: stage {A0,B0,B1,A1}(0) + A0(1); retire first 3 units ----
  STG(0, 0, 0); STG(1, 0, 0); STG(1, 1, 0); STG(0, 1, 0);
  STG(0, 0, 1);
  VMCNT(4);
  BAR();
  RD_A(af0, 0, ldsc);
  RD_B(bv0, 0, ldsc + 32768);

  // ---- main loop: j = 0..29 ----
  for (int j = 0; j < 30; ++j) {
    const char* ab  = ldsc + (size_t)(j & 1) * 65536;
    const char* bb  = ab + 32768;
    const char* abn = ldsc + (size_t)((j + 1) & 1) * 65536;
    const char* bbn = abn + 32768;
    const int nt = j + 1;
    // PhA
    RD_B(bv1, 1, bb);
    STG(1, 0, nt);
    MFMA_CL(0, 0, af0, bv0);           // C1
    VMCNT(4); BAR();
    // PhB
    RD_A(af1, 1, ab);
    STG(1, 1, nt); STG(0, 1, nt);
    MFMA_CL(0, 1, af0, bv1);           // C2
    MFMA_CL(1, 0, af1, bv0);           // C3
    VMCNT(4); BAR();
    // PhC
    RD_A(af0, 0, abn);
    RD_B(bv0, 0, bbn);
    STG(0, 0, nt + 1);
    MFMA_CL(1, 1, af1, bv1);           // C4
    VMCNT(4); BAR();
  }
  // ---- peeled j=30 (buf0): no A0(32); PhC retires B1(31) ----
  {
    const char* ab  = ldsc;
    const char* bb  = ab + 32768;
    const char* abn = ldsc + 65536;
    const char* bbn = abn + 32768;
    RD_B(bv1, 1, bb);
    STG(1, 0, 31);
    MFMA_CL(0, 0, af0, bv0);
    VMCNT(4); BAR();
    RD_A(af1, 1, ab);
    STG(1, 1, 31); STG(0, 1, 31);
    MFMA_CL(0, 1, af0, bv1);
    MFMA_CL(1, 0, af1, bv0);
    VMCNT(4); BAR();
    RD_A(af0, 0, abn);
    RD_B(bv0, 0, bbn);
    MFMA_CL(1, 1, af1, bv1);
    VMCNT(2); BAR();
  }
  // ---- peeled j=31 (buf1): drain ----
  {
    const char* ab = ldsc + 65536;
    const char* bb = ab + 32768;
    RD_B(bv1, 1, bb);
    MFMA_CL(0, 0, af0, bv0);
    VMCNT(0); BAR();
    RD_A(af1, 1, ab);
    MFMA_CL(0, 1, af0, bv1);
    MFMA_CL(1, 0, af1, bv0);
    MFMA_CL(1, 1, af1, bv1);
  }

#undef MFMA_CL
#undef RD_A
#undef RD_B
#undef STG

  // ---- epilogue: bias + per-row +/-1 (32x32 C/D layout, validated) ----
  #pragma unroll
  for (int mb = 0; mb < 4; ++mb) {
    #pragma unroll
    for (int nb = 0; nb < 2; ++nb) {
      const int col = n0 + wn * 64 + nb * 32 + (l & 31);
      const float bvs = bias[col];
      #pragma unroll
      for (int rg = 0; rg < 4; ++rg) {
        const int rowb = m0 + wm * 128 + mb * 32 + rg * 8 + 4 * (l >> 5);
        const float4 adjv = *(const float4*)&adj[rowb];
        #pragma unroll
        for (int rr = 0; rr < 4; ++rr)
          out[(size_t)(rowb + rr) * N_DIM + col] =
              acc[mb][nb][rg * 4 + rr] + bvs + adjv[rr];
      }
    }
  }
}

// ---- fallback path (ws too small): fp32 LDS-tiled GEMM + row adjust ----
__global__ __launch_bounds__(256) void k_gemm_f32(const float* __restrict__ X,
    const float* __restrict__ W, const float* __restrict__ b,
    float* __restrict__ out) {
  __shared__ float As[16][16];
  __shared__ float Bs[16][17];
  const int bn = blockIdx.x & 127, bm = blockIdx.x >> 7;
  const int tx = threadIdx.x & 15, ty = threadIdx.x >> 4;
  const int row = bm * 16 + ty, col = bn * 16 + tx;
  float acc = 0.f;
  for (int k0 = 0; k0 < K_DIM; k0 += 16) {
    As[ty][tx] = X[(size_t)row * K_DIM + k0 + tx];
    Bs[ty][tx] = W[(size_t)(k0 + ty) * N_DIM + col];
    __syncthreads();
    #pragma unroll
    for (int kk = 0; kk < 16; ++kk) acc += As[ty][kk] * Bs[kk][tx];
    __syncthreads();
  }
  out[(size_t)row * N_DIM + col] = acc + b[col];
}

__global__ __launch_bounds__(256) void k_rowadj(float* __restrict__ out) {
  const int m = blockIdx.x;
  const float c0 = out[(size_t)m * N_DIM];
  __syncthreads();
  const float a = (c0 > 0.5f) ? 1.0f : -1.0f;
  for (int n = threadIdx.x; n < N_DIM; n += 256)
    out[(size_t)m * N_DIM + n] += a;
}

extern "C" void kernel_launch(void* const* d_in, const int* in_sizes, int n_in,
                              void* d_out, int out_size, void* d_ws, size_t ws_size,
                              hipStream_t stream) {
  const float* X = (const float*)d_in[0];
  const float* W = (const float*)d_in[1];
  const float* b = (const float*)d_in[2];
  float* out = (float*)d_out;

  const size_t XB_OFF   = 0;
  const size_t WT_OFF   = (size_t)M_DIM * K_DIM * 2;        // 32 MB
  const size_t ADJ_OFF  = WT_OFF + (size_t)N_DIM * K_DIM * 2;
  const size_t WCOL_OFF = ADJ_OFF + (size_t)M_DIM * 4;
  const size_t NEED     = WCOL_OFF + (size_t)K_DIM * 4;     // ~40 MB

  if (ws_size >= NEED) {
    unsigned short* Xb  = (unsigned short*)((char*)d_ws + XB_OFF);
    unsigned short* Wt  = (unsigned short*)((char*)d_ws + WT_OFF);
    float* adj  = (float*)((char*)d_ws + ADJ_OFF);
    float* wcol = (float*)((char*)d_ws + WCOL_OFF);
    k_transW<<<dim3(1024), dim3(256), 0, stream>>>(W, Wt, wcol);
    k_convX<<<dim3(M_DIM), dim3(256), 0, stream>>>(X, wcol, b, Xb, adj);
    k_gemm8<<<dim3((M_DIM / 256) * (N_DIM / 256)), dim3(512), 0, stream>>>(
        Xb, Wt, b, adj, out);
  } else {
    k_gemm_f32<<<dim3((M_DIM / 16) * (N_DIM / 16)), dim3(256), 0, stream>>>(
        X, W, b, out);
    k_rowadj<<<dim3(M_DIM), dim3(256), 0, stream>>>(out);
  }
}

// Round 10
// 91.141 us; speedup vs baseline: 1.0917x; 1.0917x over previous
//
#include <hip/hip_runtime.h>
#include <hip/hip_bf16.h>
#include <stdint.h>

#define M_DIM 8192
#define N_DIM 2048
#define K_DIM 2048

typedef __attribute__((ext_vector_type(8))) short bf16x8;
typedef __attribute__((ext_vector_type(8))) short short8;
typedef __attribute__((ext_vector_type(4))) float f32x4;

static __device__ __forceinline__ unsigned short f2bf(float f) {
  union { float f; unsigned u; } a; a.f = f;
  unsigned u = a.u;
  u += 0x7FFFu + ((u >> 16) & 1u);   // round-to-nearest-even
  return (unsigned short)(u >> 16);
}

static __device__ __forceinline__ void async16(void* lds, const void* g) {
  __builtin_amdgcn_global_load_lds(
      (const __attribute__((address_space(1))) unsigned int*)g,
      (__attribute__((address_space(3))) unsigned int*)lds, 16, 0, 0);
}

#define BAR()                                \
  do {                                       \
    asm volatile("" ::: "memory");           \
    __builtin_amdgcn_s_barrier();            \
    asm volatile("" ::: "memory");           \
  } while (0)
#define VMCNT(n) asm volatile("s_waitcnt vmcnt(" #n ")" ::: "memory")
#define LGK()                                                \
  do {                                                       \
    asm volatile("s_waitcnt lgkmcnt(0)" ::: "memory");       \
    __builtin_amdgcn_sched_barrier(0);                       \
  } while (0)

// ---- kernel 1: convert + transpose W [K][N] -> Wt [N][K] bf16; fused
// W[:,0] extraction ----
__global__ __launch_bounds__(256) void k_transW(const float* __restrict__ W,
                                                unsigned short* __restrict__ Wt,
                                                float* __restrict__ wcol) {
  __shared__ float tile[64][65];
  const int bx = blockIdx.x & 31;
  const int by = blockIdx.x >> 5;
  const int n0 = bx * 64, k0 = by * 64;
  const int t = threadIdx.x;
  #pragma unroll
  for (int i = 0; i < 16; ++i) {
    int lin = i * 256 + t;
    int r = lin >> 6, c = lin & 63;
    float v = W[(size_t)(k0 + r) * N_DIM + n0 + c];
    tile[r][c] = v;
    if (bx == 0 && c == 0) wcol[k0 + r] = v;
  }
  __syncthreads();
  #pragma unroll
  for (int i = 0; i < 16; ++i) {
    int lin = i * 256 + t;
    int r = lin >> 6, c = lin & 63;
    Wt[(size_t)(n0 + r) * K_DIM + k0 + c] = f2bf(tile[c][r]);
  }
}

// ---- kernel 2: X fp32->bf16 + fused fp64 row-dot with W[:,0] -> adj ----
__global__ __launch_bounds__(256) void k_convX(const float* __restrict__ X,
    const float* __restrict__ wcol, const float* __restrict__ b,
    unsigned short* __restrict__ Xb, float* __restrict__ adj) {
  const int m = blockIdx.x;
  const int t = threadIdx.x;
  const float4* xr = (const float4*)(X + (size_t)m * K_DIM);
  const float4* wc = (const float4*)wcol;
  float4 x0 = xr[2 * t], x1 = xr[2 * t + 1];
  float4 w0 = wc[2 * t], w1 = wc[2 * t + 1];
  short8 o;
  o[0] = (short)f2bf(x0.x); o[1] = (short)f2bf(x0.y);
  o[2] = (short)f2bf(x0.z); o[3] = (short)f2bf(x0.w);
  o[4] = (short)f2bf(x1.x); o[5] = (short)f2bf(x1.y);
  o[6] = (short)f2bf(x1.z); o[7] = (short)f2bf(x1.w);
  *(short8*)(Xb + (size_t)m * K_DIM + t * 8) = o;
  double s = (double)x0.x * w0.x + (double)x0.y * w0.y +
             (double)x0.z * w0.z + (double)x0.w * w0.w +
             (double)x1.x * w1.x + (double)x1.y * w1.y +
             (double)x1.z * w1.z + (double)x1.w * w1.w;
  #pragma unroll
  for (int off = 32; off > 0; off >>= 1) s += __shfl_down(s, off, 64);
  __shared__ double red[4];
  if ((t & 63) == 0) red[t >> 6] = s;
  __syncthreads();
  if (t == 0) {
    double tot = red[0] + red[1] + red[2] + red[3] + (double)b[0];
    adj[m] = (tot > 0.5) ? 1.0f : -1.0f;
  }
}

// ---- kernel 3: 256x256 m201-style 8-phase GEMM, 16x16x32 MFMA ----
// LDS/fragment layout = rounds 3/4 (HW-validated, 0 bank conflicts):
// subtile [16r x 32k] = 1024B; rdoff = (r*64+q*16)^((r&8)<<2); stage via
// pre-swizzled global col. 8 phases / 2 K-tiles; per phase: reads for THIS
// phase's quadrant, 1 stage unit, BAR, lgkmcnt(0), setprio, 16 MFMA,
// setprio, [vmcnt(4) at ph4/ph8], BAR.
// Stage map (iter i): ph1 B1(2i+1) ph2 A1(2i+1) ph3 A0(2i+2) ph4 B0(2i+2)
//                     ph5 B1(2i+2) ph6 A1(2i+2) ph7 A0(2i+3) ph8 B0(2i+3)
// FIFO trace: vmcnt(4)@ph4 retires all of tile 2i+1 (before ph5 reads);
// vmcnt(4)@ph8 retires all of tile 2i+2 (before next ph1). Every stage
// issues >=1 barrier after its LDS region's last reader (A0 rd ph1,
// B0 ph1, B1 ph2, A1 ph3 within each 4-phase group). Never <4 in flight.
__device__ __forceinline__ void stage_unit(char* ldsc,
    const unsigned short* __restrict__ src, int row0, int kt,
    int isB, int sel, int wid, int l) {
  char* base = ldsc + (size_t)(kt & 1) * 65536 + (size_t)isB * 32768;
  #pragma unroll
  for (int j = 0; j < 2; ++j) {
    int s = wid * 2 + j;               // [0,16) subtile slots of this unit
    int sub_c = s & 1;
    int idx = s >> 1;                  // [0,8)
    int sub_r = isB ? ((idx & 1) + (idx >> 1) * 4 + sel * 2)
                    : ((idx & 3) + ((idx & 4) ? 8 : 0) + sel * 4);
    int grow = row0 + sub_r * 16 + (l >> 2);
    int gcol = kt * 64 + sub_c * 32 + (((l & 3) * 8) ^ ((l & 32) >> 1));
    async16(base + (size_t)(sub_r * 2 + sub_c) * 1024,
            src + (size_t)grow * K_DIM + gcol);
  }
}

__global__ __launch_bounds__(512, 1) void k_gemm8(
    const unsigned short* __restrict__ A,   // Xb [M][K] bf16
    const unsigned short* __restrict__ B,   // Wt [N][K] bf16
    const float* __restrict__ bias,
    const float* __restrict__ adj,
    float* __restrict__ out) {
  __shared__ unsigned short lds[2 * 2 * 256 * 64];   // 128 KB
  char* ldsc = (char*)lds;

  const int t = threadIdx.x;
  const int wid = t >> 6, l = t & 63;
  const int wm = wid >> 2, wn = wid & 3;

  // XCD-bijective swizzle (nwg = 256, 256 % 8 == 0)
  const int bid = blockIdx.x;
  const int swz = (bid & 7) * 32 + (bid >> 3);
  const int bm = swz >> 3, bn = swz & 7;
  const int m0 = bm * 256, n0 = bn * 256;

  const int r = l & 15, q = l >> 4;
  const int rdoff = (r * 64 + q * 16) ^ ((r & 8) << 2);

  const char* ab0 = ldsc;
  const char* bb0 = ldsc + 32768;
  const char* ab1 = ldsc + 65536;
  const char* bb1 = ldsc + 98304;

  f32x4 acc[8][4] = {};
  bf16x8 af0[2][4], af1[2][4], bv0[2][2], bv1[2][2];

#define STG(isB, sel, kt) \
  stage_unit(ldsc, (isB) ? B : A, (isB) ? n0 : m0, kt, isB, sel, wid, l)

#define RD_A(DST, MH, AB)                                                   \
  _Pragma("unroll") for (int mi4 = 0; mi4 < 4; ++mi4) {                     \
    const int sub_r = wm * 8 + (MH) * 4 + mi4;                              \
    _Pragma("unroll") for (int ks = 0; ks < 2; ++ks)                        \
      DST[ks][mi4] =                                                        \
          *(const bf16x8*)((AB) + (size_t)(sub_r * 2 + ks) * 1024 + rdoff); \
  }

#define RD_B(DST, NH, BB)                                                   \
  _Pragma("unroll") for (int ni2 = 0; ni2 < 2; ++ni2) {                     \
    const int sub_r = wn * 4 + (NH) * 2 + ni2;                              \
    _Pragma("unroll") for (int ks = 0; ks < 2; ++ks)                        \
      DST[ks][ni2] =                                                        \
          *(const bf16x8*)((BB) + (size_t)(sub_r * 2 + ks) * 1024 + rdoff); \
  }

#define CL(MH, NH, AF, BV)                                                  \
  __builtin_amdgcn_s_setprio(1);                                            \
  _Pragma("unroll") for (int ks = 0; ks < 2; ++ks)                          \
    _Pragma("unroll") for (int mi4 = 0; mi4 < 4; ++mi4)                     \
      _Pragma("unroll") for (int ni2 = 0; ni2 < 2; ++ni2)                   \
        acc[(MH) * 4 + mi4][(NH) * 2 + ni2] =                               \
            __builtin_amdgcn_mfma_f32_16x16x32_bf16(                        \
                AF[ks][mi4], BV[ks][ni2],                                   \
                acc[(MH) * 4 + mi4][(NH) * 2 + ni2], 0, 0, 0);              \
  __builtin_amdgcn_s_setprio(0);

#define PH(RD_STMT, STG_STMT, CL_STMT, WAIT_STMT)                           \
  {                                                                         \
    RD_STMT;                                                                \
    STG_STMT;                                                               \
    BAR();                                                                  \
    LGK();                                                                  \
    CL_STMT;                                                                \
    WAIT_STMT;                                                              \
    BAR();                                                                  \
  }

  // ---- prologue: tile 0 (A0,B0,B1,A1) + A0(1),B0(1); retire tile 0 ----
  STG(0, 0, 0); STG(1, 0, 0); STG(1, 1, 0); STG(0, 1, 0);
  STG(0, 0, 1); STG(1, 0, 1);
  VMCNT(4);
  BAR();

  // ---- main loop: 15 iters, 2 K-tiles each ----
  for (int i = 0; i < 15; ++i) {
    const int t1 = 2 * i + 1, t2 = 2 * i + 2, t3 = 2 * i + 3;
    PH(RD_A(af0, 0, ab0); RD_B(bv0, 0, bb0), STG(1, 1, t1),
       CL(0, 0, af0, bv0), );                                   // ph1
    PH(RD_B(bv1, 1, bb0), STG(0, 1, t1), CL(0, 1, af0, bv1), ); // ph2
    PH(RD_A(af1, 1, ab0), STG(0, 0, t2), CL(1, 0, af1, bv0), ); // ph3
    PH(, STG(1, 0, t2), CL(1, 1, af1, bv1), VMCNT(4));          // ph4
    PH(RD_A(af0, 0, ab1); RD_B(bv0, 0, bb1), STG(1, 1, t2),
       CL(0, 0, af0, bv0), );                                   // ph5
    PH(RD_B(bv1, 1, bb1), STG(0, 1, t2), CL(0, 1, af0, bv1), ); // ph6
    PH(RD_A(af1, 1, ab1), STG(0, 0, t3), CL(1, 0, af1, bv0), ); // ph7
    PH(, STG(1, 0, t3), CL(1, 1, af1, bv1), VMCNT(4));          // ph8
  }
  // ---- peeled iter 15 (tiles 30, 31) ----
  PH(RD_A(af0, 0, ab0); RD_B(bv0, 0, bb0), STG(1, 1, 31),
     CL(0, 0, af0, bv0), );
  PH(RD_B(bv1, 1, bb0), STG(0, 1, 31), CL(0, 1, af0, bv1), );
  PH(RD_A(af1, 1, ab0), , CL(1, 0, af1, bv0), );
  PH(, , CL(1, 1, af1, bv1), VMCNT(0));                         // tile 31 landed
  PH(RD_A(af0, 0, ab1); RD_B(bv0, 0, bb1), , CL(0, 0, af0, bv0), );
  PH(RD_B(bv1, 1, bb1), , CL(0, 1, af0, bv1), );
  PH(RD_A(af1, 1, ab1), , CL(1, 0, af1, bv0), );
  PH(, , CL(1, 1, af1, bv1), );

#undef PH
#undef CL
#undef RD_A
#undef RD_B
#undef STG

  // ---- epilogue: bias + per-row +/-1 (16x16 C/D layout, r3/4-validated) ----
  #pragma unroll
  for (int mi = 0; mi < 8; ++mi) {
    const int rowb = m0 + wm * 128 + mi * 16 + q * 4;
    float adjv[4];
    #pragma unroll
    for (int j = 0; j < 4; ++j) adjv[j] = adj[rowb + j];
    #pragma unroll
    for (int ni = 0; ni < 4; ++ni) {
      const int col = n0 + wn * 64 + ni * 16 + r;
      const float bvs = bias[col];
      #pragma unroll
      for (int j = 0; j < 4; ++j)
        out[(size_t)(rowb + j) * N_DIM + col] = acc[mi][ni][j] + bvs + adjv[j];
    }
  }
}

// ---- fallback path (ws too small): fp32 LDS-tiled GEMM + row adjust ----
__global__ __launch_bounds__(256) void k_gemm_f32(const float* __restrict__ X,
    const float* __restrict__ W, const float* __restrict__ b,
    float* __restrict__ out) {
  __shared__ float As[16][16];
  __shared__ float Bs[16][17];
  const int bn = blockIdx.x & 127, bm = blockIdx.x >> 7;
  const int tx = threadIdx.x & 15, ty = threadIdx.x >> 4;
  const int row = bm * 16 + ty, col = bn * 16 + tx;
  float acc = 0.f;
  for (int k0 = 0; k0 < K_DIM; k0 += 16) {
    As[ty][tx] = X[(size_t)row * K_DIM + k0 + tx];
    Bs[ty][tx] = W[(size_t)(k0 + ty) * N_DIM + col];
    __syncthreads();
    #pragma unroll
    for (int kk = 0; kk < 16; ++kk) acc += As[ty][kk] * Bs[kk][tx];
    __syncthreads();
  }
  out[(size_t)row * N_DIM + col] = acc + b[col];
}

__global__ __launch_bounds__(256) void k_rowadj(float* __restrict__ out) {
  const int m = blockIdx.x;
  const float c0 = out[(size_t)m * N_DIM];
  __syncthreads();
  const float a = (c0 > 0.5f) ? 1.0f : -1.0f;
  for (int n = threadIdx.x; n < N_DIM; n += 256)
    out[(size_t)m * N_DIM + n] += a;
}

extern "C" void kernel_launch(void* const* d_in, const int* in_sizes, int n_in,
                              void* d_out, int out_size, void* d_ws, size_t ws_size,
                              hipStream_t stream) {
  const float* X = (const float*)d_in[0];
  const float* W = (const float*)d_in[1];
  const float* b = (const float*)d_in[2];
  float* out = (float*)d_out;

  const size_t XB_OFF   = 0;
  const size_t WT_OFF   = (size_t)M_DIM * K_DIM * 2;        // 32 MB
  const size_t ADJ_OFF  = WT_OFF + (size_t)N_DIM * K_DIM * 2;
  const size_t WCOL_OFF = ADJ_OFF + (size_t)M_DIM * 4;
  const size_t NEED     = WCOL_OFF + (size_t)K_DIM * 4;     // ~40 MB

  if (ws_size >= NEED) {
    unsigned short* Xb  = (unsigned short*)((char*)d_ws + XB_OFF);
    unsigned short* Wt  = (unsigned short*)((char*)d_ws + WT_OFF);
    float* adj  = (float*)((char*)d_ws + ADJ_OFF);
    float* wcol = (float*)((char*)d_ws + WCOL_OFF);
    k_transW<<<dim3(1024), dim3(256), 0, stream>>>(W, Wt, wcol);
    k_convX<<<dim3(M_DIM), dim3(256), 0, stream>>>(X, wcol, b, Xb, adj);
    k_gemm8<<<dim3((M_DIM / 256) * (N_DIM / 256)), dim3(512), 0, stream>>>(
        Xb, Wt, b, adj, out);
  } else {
    k_gemm_f32<<<dim3((M_DIM / 16) * (N_DIM / 16)), dim3(256), 0, stream>>>(
        X, W, b, out);
    k_rowadj<<<dim3(M_DIM), dim3(256), 0, stream>>>(out);
  }
}